// Round 10
// baseline (669.488 us; speedup 1.0000x reference)
//
#include <hip/hip_runtime.h>
#include <hip/hip_bf16.h>
#include <cstdio>

typedef __bf16  bf16x8 __attribute__((ext_vector_type(8)));
typedef float   f32x4  __attribute__((ext_vector_type(4)));
typedef unsigned short u16;
typedef u16     u16x8  __attribute__((ext_vector_type(8)));
typedef u16     u16x4  __attribute__((ext_vector_type(4)));

enum { EPI_QKV = 0, EPI_QK = 1, EPI_PV = 2 };

// ---------- helpers ----------

__device__ __forceinline__ void gld_lds16(const void* g, void* l) {
  // async global->LDS, 16B per lane; LDS dest is wave-uniform base + lane*16
  __builtin_amdgcn_global_load_lds(
      (const __attribute__((address_space(1))) unsigned int*)g,
      (__attribute__((address_space(3))) unsigned int*)l,
      16, 0, 0);
}

__device__ __forceinline__ u16 f2bf(float f) {
  union { float f; unsigned int u; } c{f};
  unsigned int u = c.u;
  u += 0x7fffu + ((u >> 16) & 1u);   // round-to-nearest-even
  return (u16)(u >> 16);
}

// ---------- device-wide barrier ----------
// 256 blocks x 1/CU (128 KiB LDS forces 1 block/CU; grid == CU count) -> all
// blocks resident by construction -> arrive-and-spin barrier is deadlock-free.
// __threadfence() = agent-scope fence: L2 writeback on release / invalidate on
// acquire (required: per-XCD L2s are not cross-coherent). Counter is monotonic
// within a launch (bucket formula); host zeroes it each launch.

__device__ __forceinline__ void grid_bar(unsigned int* ctr) {
  __threadfence();                                   // release phase data
  __syncthreads();
  if (threadIdx.x == 0) {
    unsigned int old = __hip_atomic_fetch_add(ctr, 1u, __ATOMIC_ACQ_REL,
                                              __HIP_MEMORY_SCOPE_AGENT);
    unsigned int tgt = (old / 256u + 1u) * 256u;
    while (__hip_atomic_load(ctr, __ATOMIC_ACQUIRE, __HIP_MEMORY_SCOPE_AGENT) < tgt)
      __builtin_amdgcn_s_sleep(8);
  }
  __syncthreads();
  __threadfence();                                   // acquire others' data
}

// ---------- legacy 128x128 BT-GEMM tile as a device function ----------
// Runs on a 256-thread SUB-BLOCK (ts in [0,256)) with a private 34816-B LDS
// slice. __syncthreads() is block-wide (both sub-blocks execute identical
// barrier counts per tile: 2 per K-step + 2 in every epilogue path).
// EPI_QKV: n0<2048 dense Q/K stores (+2 alignment barriers); n0>=2048
// V-transpose through LDS -> VT. EPI_PV: self-computed rowsum (verified r8/r9).

template <int EPI>
__device__ void gemm128_tile(const u16* __restrict__ A, const u16* __restrict__ B,
                             void* __restrict__ Cv, int K, int lda, int ldb, int ldc,
                             long sA, long sB, long sC,
                             u16* __restrict__ auxK, u16* __restrict__ auxV,
                             u16* slds, int ts, int bxs, int bys, int bz) {
  u16* As = slds;
  u16* Bs = slds + 128 * 64;

  const int w = ts >> 6, l = ts & 63;
  const u16* Ab = A + (long)bz * sA;
  const u16* Bb = B + (long)bz * sB;
  const int m0 = bys * 128, n0 = bxs * 128;
  const int wm = w & 1, wn = w >> 1;
  const int lr = l & 15, lq = l >> 4;
  const int srow = l >> 3;
  const int scol = ((l & 7) ^ ((l >> 3) & 7)) * 8;
  const int rsw = l & 7;

  f32x4 acc[4][4] = {};
  float rsp[4] = {0.f, 0.f, 0.f, 0.f};   // EPI_PV: per-lane partial rowsums

  for (int k0 = 0; k0 < K; k0 += 64) {
    __syncthreads();
#pragma unroll
    for (int c = 0; c < 4; ++c) {
      const int rb = (w * 4 + c) * 8;
      gld_lds16(Ab + (long)(m0 + rb + srow) * lda + k0 + scol, (void*)(As + rb * 64));
      gld_lds16(Bb + (long)(n0 + rb + srow) * ldb + k0 + scol, (void*)(Bs + rb * 64));
    }
    __syncthreads();
#pragma unroll
    for (int j = 0; j < 2; ++j) {
      bf16x8 af[4], bfr[4];
#pragma unroll
      for (int i = 0; i < 4; ++i) {
        const int ch = ((j * 4 + lq) ^ rsw) * 8;
        af[i]  = *(const bf16x8*)(As + (wm * 64 + i * 16 + lr) * 64 + ch);
        bfr[i] = *(const bf16x8*)(Bs + (wn * 64 + i * 16 + lr) * 64 + ch);
      }
      if (EPI == EPI_PV) {
#pragma unroll
        for (int i = 0; i < 4; ++i)
#pragma unroll
          for (int e = 0; e < 8; ++e)
            rsp[i] += (float)af[i][e];
      }
#pragma unroll
      for (int mi = 0; mi < 4; ++mi)
#pragma unroll
        for (int ni = 0; ni < 4; ++ni)
          acc[mi][ni] = __builtin_amdgcn_mfma_f32_16x16x32_bf16(af[mi], bfr[ni], acc[mi][ni], 0, 0, 0);
    }
  }

  if (EPI == EPI_PV) {
#pragma unroll
    for (int i = 0; i < 4; ++i) {
      rsp[i] += __shfl_xor(rsp[i], 16, 64);
      rsp[i] += __shfl_xor(rsp[i], 32, 64);
    }
  }

  if (EPI == EPI_QKV && n0 >= 2048) {
    // ---- V slice: transpose 128x128 tile through LDS, coalesced stores ----
    u16* tp = slds;  // [128 cols][136 rows-padded] u16 = 34816 B
    __syncthreads();
#pragma unroll
    for (int mi = 0; mi < 4; ++mi) {
      const int row0 = wm * 64 + mi * 16 + lq * 4;
#pragma unroll
      for (int ni = 0; ni < 4; ++ni) {
        const int col = wn * 64 + ni * 16 + lr;
        u16x4 v4;
#pragma unroll
        for (int i = 0; i < 4; ++i) v4[i] = f2bf(acc[mi][ni][i]);
        *(u16x4*)(tp + col * 136 + row0) = v4;
      }
    }
    __syncthreads();
    const int e0 = n0 - 2048;
    const long bb = m0 >> 11;
    const int kbase = m0 & 2047;
    u16* vt_base = auxV + bb * 2097152;
#pragma unroll
    for (int q = 0; q < 8; ++q) {
      const int chunk = q * 256 + ts;
      const int c = chunk >> 4, r0 = (chunk & 15) * 8;
      u16x8 v = *(const u16x8*)(tp + c * 136 + r0);
      *(u16x8*)(vt_base + (long)(e0 + c) * 2048 + kbase + r0) = v;
    }
    return;
  }

  if (EPI == EPI_QKV) __syncthreads();   // barrier-count alignment w/ V path

  u16* qkv_out = nullptr;
  int nl0 = 0;
  if (EPI == EPI_QKV) {
    qkv_out = (n0 < 1024) ? (u16*)Cv : auxK;
    nl0 = n0 & 1023;
  }

#pragma unroll
  for (int mi = 0; mi < 4; ++mi) {
#pragma unroll
    for (int i = 0; i < 4; ++i) {
      const int row = m0 + wm * 64 + mi * 16 + lq * 4 + i;
      float inv;
      if (EPI == EPI_PV) {
        const float rstot = __shfl(rsp[mi], lq * 4 + i, 64);
        inv = 1.0f / rstot;
      }
#pragma unroll
      for (int ni = 0; ni < 4; ++ni) {
        const float val = acc[mi][ni][i];
        const int col = n0 + wn * 64 + ni * 16 + lr;
        if (EPI == EPI_QKV) {
          qkv_out[(long)row * 1024 + nl0 + wn * 64 + ni * 16 + lr] = f2bf(val);
        } else {  // EPI_PV
          ((float*)Cv)[(long)bz * sC + (long)row * ldc + col] = val * inv;
        }
      }
    }
  }

  if (EPI == EPI_QKV) __syncthreads();   // barrier-count alignment w/ V path
}

// ---------- 256x256 8-phase QK tile (full 512-thread block) ----------
// Verbatim r4/r9 schedule; atomic-free exp+store epilogue.

__device__ __forceinline__ void stage_half(const u16* __restrict__ g, int ld, int k0,
                                           u16* ldsb, int w, int l) {
  const int srow = l >> 3;
  const int scol = ((l & 7) ^ (srow & 7)) * 8;
#pragma unroll
  for (int q = 0; q < 2; ++q) {
    const int r = w * 16 + q * 8;
    gld_lds16(g + (long)(r + srow) * ld + k0 + scol, (void*)(ldsb + r * 64));
  }
}

__device__ void gemm256_qk(const u16* __restrict__ A, const u16* __restrict__ B,
                           u16* __restrict__ SPo, u16* lds, int t,
                           int bxs, int bys, int bz) {
  const int w = t >> 6, l = t & 63;
  const int wm = w >> 2, wn = w & 3;
  const int lr = l & 15, lq = l >> 4;
  const int rsw = l & 7;
  const int m0 = bys * 256, n0 = bxs * 256;
  const int lda = 1024, ldb = 1024, ldc = 2048, K = 1024;
  const long sA = 2048L * 1024, sB = 2048L * 1024, sC = 2048L * 2048;
  const u16* Ar = A + (long)bz * sA + (long)m0 * lda;
  const u16* Br = B + (long)bz * sB + (long)n0 * ldb;

  u16* curA = lds;
  u16* curB = lds + 16384;
  u16* nxtA = lds + 32768;
  u16* nxtB = lds + 49152;

  const int nt = K >> 6;

  f32x4 acc[8][4] = {};

  stage_half(Ar,             lda, 0, curA,        w, l);
  stage_half(Br,             ldb, 0, curB,        w, l);
  stage_half(Br + 128 * ldb, ldb, 0, curB + 8192, w, l);
  stage_half(Ar + 128 * lda, lda, 0, curA + 8192, w, l);
  asm volatile("s_waitcnt vmcnt(4)" ::: "memory");
  if (nt > 1) {
    stage_half(Ar,             lda, 64, nxtA,        w, l);
    stage_half(Br,             ldb, 64, nxtB,        w, l);
    stage_half(Br + 128 * ldb, ldb, 64, nxtB + 8192, w, l);
    asm volatile("s_waitcnt vmcnt(6)" ::: "memory");
  } else {
    asm volatile("s_waitcnt vmcnt(0)" ::: "memory");
  }
  __builtin_amdgcn_s_barrier();

  for (int tt = 0; tt < nt; ++tt) {
    const int kc = tt << 6;
    bf16x8 a0[4][2], a1[4][2], b0[2][2], b1[2][2];

    // P1
#pragma unroll
    for (int mi = 0; mi < 4; ++mi)
#pragma unroll
      for (int j = 0; j < 2; ++j)
        a0[mi][j] = *(const bf16x8*)(curA + (wm * 128 + mi * 16 + lr) * 64 +
                                     (((j * 4 + lq) ^ rsw) * 8));
#pragma unroll
    for (int ni = 0; ni < 2; ++ni)
#pragma unroll
      for (int j = 0; j < 2; ++j)
        b0[ni][j] = *(const bf16x8*)(curB + (wn * 64 + ni * 16 + lr) * 64 +
                                     (((j * 4 + lq) ^ rsw) * 8));
    if (tt + 1 < nt)
      stage_half(Ar + 128 * lda, lda, kc + 64, nxtA + 8192, w, l);
    __builtin_amdgcn_s_barrier();
    asm volatile("s_waitcnt lgkmcnt(0)" ::: "memory");
    __builtin_amdgcn_sched_barrier(0);
    __builtin_amdgcn_s_setprio(1);
#pragma unroll
    for (int mi = 0; mi < 4; ++mi)
#pragma unroll
      for (int ni = 0; ni < 2; ++ni)
#pragma unroll
        for (int j = 0; j < 2; ++j)
          acc[mi][ni] = __builtin_amdgcn_mfma_f32_16x16x32_bf16(a0[mi][j], b0[ni][j], acc[mi][ni], 0, 0, 0);
    __builtin_amdgcn_s_setprio(0);
    __builtin_amdgcn_s_barrier();

    // P2
#pragma unroll
    for (int ni = 0; ni < 2; ++ni)
#pragma unroll
      for (int j = 0; j < 2; ++j)
        b1[ni][j] = *(const bf16x8*)(curB + (wn * 64 + (ni + 2) * 16 + lr) * 64 +
                                     (((j * 4 + lq) ^ rsw) * 8));
    __builtin_amdgcn_s_barrier();
    asm volatile("s_waitcnt lgkmcnt(0)" ::: "memory");
    __builtin_amdgcn_sched_barrier(0);
    __builtin_amdgcn_s_setprio(1);
#pragma unroll
    for (int mi = 0; mi < 4; ++mi)
#pragma unroll
      for (int ni = 0; ni < 2; ++ni)
#pragma unroll
        for (int j = 0; j < 2; ++j)
          acc[mi][ni + 2] = __builtin_amdgcn_mfma_f32_16x16x32_bf16(a0[mi][j], b1[ni][j], acc[mi][ni + 2], 0, 0, 0);
    __builtin_amdgcn_s_setprio(0);
    __builtin_amdgcn_s_barrier();

    // P3
#pragma unroll
    for (int mi = 0; mi < 4; ++mi)
#pragma unroll
      for (int j = 0; j < 2; ++j)
        a1[mi][j] = *(const bf16x8*)(curA + (wm * 128 + (mi + 4) * 16 + lr) * 64 +
                                     (((j * 4 + lq) ^ rsw) * 8));
    if (tt + 2 < nt)
      stage_half(Br, ldb, kc + 128, curB, w, l);
    __builtin_amdgcn_s_barrier();
    asm volatile("s_waitcnt lgkmcnt(0)" ::: "memory");
    __builtin_amdgcn_sched_barrier(0);
    __builtin_amdgcn_s_setprio(1);
#pragma unroll
    for (int mi = 0; mi < 4; ++mi)
#pragma unroll
      for (int ni = 0; ni < 2; ++ni)
#pragma unroll
        for (int j = 0; j < 2; ++j)
          acc[mi + 4][ni + 2] = __builtin_amdgcn_mfma_f32_16x16x32_bf16(a1[mi][j], b1[ni][j], acc[mi + 4][ni + 2], 0, 0, 0);
    __builtin_amdgcn_s_setprio(0);
    __builtin_amdgcn_s_barrier();

    // P4
    if (tt + 2 < nt) {
      stage_half(Br + 128 * ldb, ldb, kc + 128, curB + 8192, w, l);
      stage_half(Ar,             lda, kc + 128, curA,        w, l);
    }
    __builtin_amdgcn_s_barrier();
    __builtin_amdgcn_sched_barrier(0);
    __builtin_amdgcn_s_setprio(1);
#pragma unroll
    for (int mi = 0; mi < 4; ++mi)
#pragma unroll
      for (int ni = 0; ni < 2; ++ni)
#pragma unroll
        for (int j = 0; j < 2; ++j)
          acc[mi + 4][ni] = __builtin_amdgcn_mfma_f32_16x16x32_bf16(a1[mi][j], b0[ni][j], acc[mi + 4][ni], 0, 0, 0);
    __builtin_amdgcn_s_setprio(0);
    if (tt + 2 < nt)      asm volatile("s_waitcnt vmcnt(6)" ::: "memory");
    else if (tt + 1 < nt) asm volatile("s_waitcnt vmcnt(0)" ::: "memory");
    __builtin_amdgcn_s_barrier();

    { u16* x_ = curA; curA = nxtA; nxtA = x_; }
    { u16* y_ = curB; curB = nxtB; nxtB = y_; }
  }

  // epilogue: pure exp+store (rowsum computed in PV)
#pragma unroll
  for (int mi = 0; mi < 8; ++mi) {
#pragma unroll
    for (int i = 0; i < 4; ++i) {
      const int row = m0 + wm * 128 + mi * 16 + lq * 4 + i;
#pragma unroll
      for (int ni = 0; ni < 4; ++ni) {
        const int col = n0 + wn * 64 + ni * 16 + lr;
        const u16 h = f2bf(__expf(acc[mi][ni][i] * 0.03125f));
        SPo[(long)bz * sC + (long)row * ldc + col] = h;
      }
    }
  }
}

// ---------- fused pipeline: prep | QKV | QK | PV, one launch ----------
// 256 blocks x 512 threads, 128 KiB LDS -> exactly 1 block/CU, all resident.
// Legacy phases run as 2 independent 256-thread sub-blocks per block (each
// with a 34816-B LDS slice = the measured-best 2-legacy-blocks/CU config);
// QK runs the native 512-thread gemm256 tile. Tile maps keep XCD contiguity:
// XCD x = blk&7 owns a contiguous range of logical tiles.

__global__ __launch_bounds__(512, 2)
void fused_attn(const float* __restrict__ x, const float* __restrict__ w,
                u16* __restrict__ xbf, u16* __restrict__ wt,
                u16* __restrict__ Qc, u16* __restrict__ Kc,
                u16* __restrict__ VT, u16* __restrict__ SP,
                float* __restrict__ out, unsigned int* __restrict__ ctr) {
  __shared__ __align__(16) u16 lds[65536];   // 128 KiB
  const int blk = blockIdx.x;                // 0..255
  const int t = threadIdx.x;                 // 0..511
  const int sb = t >> 8, ts = t & 255;
  u16* slds = lds + sb * 17408;              // 34816 B per sub-block

  // ---- phase 0: prep (cast x->bf16; transpose weights). 512 workers x 14 --
  {
    const int vw = blk * 2 + sb;
    float* tile = (float*)slds;              // [32][33] floats
#pragma unroll 1
    for (int j = 0; j < 14; ++j) {
      const int bid = vw * 14 + j;           // 0..7167
      if (bid < 4096) {
        const int i = (bid * 256 + ts) * 8;
        float4 a = *(const float4*)(x + i);
        float4 b = *(const float4*)(x + i + 4);
        u16x8 r;
        r[0] = f2bf(a.x); r[1] = f2bf(a.y); r[2] = f2bf(a.z); r[3] = f2bf(a.w);
        r[4] = f2bf(b.x); r[5] = f2bf(b.y); r[6] = f2bf(b.z); r[7] = f2bf(b.w);
        *(u16x8*)(xbf + i) = r;
        __syncthreads();
        __syncthreads();                     // barrier-count alignment
      } else {
        const int b2 = bid - 4096;
        const int s = b2 >> 10, rr = b2 & 1023;
        const int e0 = (rr & 31) * 32, d0 = (rr >> 5) * 32;
        const int tx = ts & 31, ty = ts >> 5;
        const float* in = w + (size_t)s * 1048576;
#pragma unroll
        for (int jj = 0; jj < 4; ++jj)
          tile[(ty + jj * 8) * 33 + tx] = in[(size_t)(d0 + ty + jj * 8) * 1024 + e0 + tx];
        __syncthreads();
        u16* o = wt + (size_t)s * 1048576;
#pragma unroll
        for (int jj = 0; jj < 4; ++jj)
          o[(size_t)(e0 + ty + jj * 8) * 1024 + d0 + tx] = f2bf(tile[tx * 33 + ty + jj * 8]);
        __syncthreads();                     // tile reuse guard
      }
    }
  }
  grid_bar(ctr);

  // ---- phase 1: QKV projections, 1536 legacy tiles (3 per sub-block) ------
  {
#pragma unroll 1
    for (int j = 0; j < 3; ++j) {
      const int l1536 = (blk & 7) * 192 + (blk >> 3) * 6 + sb * 3 + j;
      const int bxs = l1536 % 24, bys = l1536 / 24;
      gemm128_tile<EPI_QKV>(xbf, wt, Qc, 1024, 1024, 1024, 1024, 0, 0, 0,
                            Kc, VT, slds, ts, bxs, bys, 0);
    }
  }
  grid_bar(ctr);

  // ---- phase 2: QK -> SP, 256 gemm256 tiles (1 per block, full 512 thr) ---
  {
    const int l256 = (blk & 7) * 32 + (blk >> 3);
    gemm256_qk(Qc, Kc, SP, lds, t, l256 & 7, (l256 >> 3) & 7, l256 >> 6);
  }
  grid_bar(ctr);

  // ---- phase 3: PV -> out, 512 legacy tiles (1 per sub-block) -------------
  {
    const int l512 = (blk & 7) * 64 + (blk >> 3) * 2 + sb;
    gemm128_tile<EPI_PV>(SP, VT, out, 2048, 2048, 2048, 1024,
                         2048L * 2048, 1024L * 2048, 2048L * 1024,
                         nullptr, nullptr, slds, ts,
                         l512 & 7, (l512 >> 3) & 15, l512 >> 7);
  }
}

// ---------- launch ----------

extern "C" void kernel_launch(void* const* d_in, const int* in_sizes, int n_in,
                              void* d_out, int out_size, void* d_ws, size_t ws_size,
                              hipStream_t stream) {
  (void)in_sizes; (void)n_in; (void)out_size;
  const float* x    = (const float*)d_in[0];
  const float* kern = (const float*)d_in[1];
  float* out = (float*)d_out;
  char* ws = (char*)d_ws;
  const size_t MB = 1024 * 1024;
  u16*   xbf  = (u16*)(ws);              // 16 MB: [8192][1024] bf16
  u16*   WT   = (u16*)(ws + 16 * MB);    //  6 MB: [3][1024][1024] bf16
  u16*   Qc   = (u16*)(ws + 22 * MB);    // 16 MB: [8192][1024] bf16
  u16*   Kc   = (u16*)(ws + 38 * MB);    // 16 MB: [8192][1024] bf16
  u16*   VT   = (u16*)(ws + 54 * MB);    // 16 MB: [4][1024e][2048k] bf16
  u16*   SP   = (u16*)(ws + 70 * MB);    // 32 MB: [4][2048][2048] bf16 unnorm probs
  unsigned int* CTR = (unsigned int*)(ws + 102 * MB);  // grid-barrier counter
  if (ws_size < 102 * MB + 64)
    fprintf(stderr, "WARNING: ws_size %zu too small\n", ws_size);

  hipMemsetAsync(CTR, 0, 4, stream);     // barrier epoch reset (capture-safe)
  fused_attn<<<dim3(256), dim3(512), 0, stream>>>(
      x, kern, xbf, WT, Qc, Kc, VT, SP, out, CTR);
}

// Round 11
// 236.667 us; speedup vs baseline: 2.8288x; 2.8288x over previous
//
#include <hip/hip_runtime.h>
#include <hip/hip_bf16.h>
#include <cstdio>

typedef __bf16  bf16x8 __attribute__((ext_vector_type(8)));
typedef float   f32x4  __attribute__((ext_vector_type(4)));
typedef unsigned short u16;
typedef u16     u16x8  __attribute__((ext_vector_type(8)));
typedef u16     u16x4  __attribute__((ext_vector_type(4)));

// ---------- helpers ----------

__device__ __forceinline__ void gld_lds16(const void* g, void* l) {
  // async global->LDS, 16B per lane; LDS dest is wave-uniform base + lane*16
  __builtin_amdgcn_global_load_lds(
      (const __attribute__((address_space(1))) unsigned int*)g,
      (__attribute__((address_space(3))) unsigned int*)l,
      16, 0, 0);
}

__device__ __forceinline__ u16 f2bf(float f) {
  union { float f; unsigned int u; } c{f};
  unsigned int u = c.u;
  u += 0x7fffu + ((u >> 16) & 1u);   // round-to-nearest-even
  return (u16)(u >> 16);
}

__device__ __forceinline__ float bf2f(u16 h) {
  union { unsigned int u; float f; } c{(unsigned int)h << 16};
  return c.f;
}

enum { EPI_QKV = 0, EPI_QK = 1, EPI_PV = 2 };

// ---------- prep: cast x -> bf16, pack/transpose weights ----------
// grid: [0,4096) cast blocks, [4096,7168) weight tiles

__global__ __launch_bounds__(256) void prep_kernel(const float* __restrict__ x,
                                                   u16* __restrict__ xbf,
                                                   const float* __restrict__ w,
                                                   u16* __restrict__ wt) {
  __shared__ float tile[32][33];
  const int bid = blockIdx.x;
  if (bid < 4096) {
    const int i = (bid * 256 + threadIdx.x) * 8;
    float4 a = *(const float4*)(x + i);
    float4 b = *(const float4*)(x + i + 4);
    u16x8 r;
    r[0] = f2bf(a.x); r[1] = f2bf(a.y); r[2] = f2bf(a.z); r[3] = f2bf(a.w);
    r[4] = f2bf(b.x); r[5] = f2bf(b.y); r[6] = f2bf(b.z); r[7] = f2bf(b.w);
    *(u16x8*)(xbf + i) = r;
  } else {
    // WT[s][e][d] = w[s][d][e], s in 0..2
    const int b2 = bid - 4096;
    const int s = b2 >> 10, r = b2 & 1023;
    const int e0 = (r & 31) * 32, d0 = (r >> 5) * 32;
    const int tx = threadIdx.x & 31, ty = threadIdx.x >> 5;
    const float* in = w + (size_t)s * 1048576;
#pragma unroll
    for (int j = 0; j < 4; ++j)
      tile[ty + j * 8][tx] = in[(size_t)(d0 + ty + j * 8) * 1024 + e0 + tx];
    __syncthreads();
    u16* o = wt + (size_t)s * 1048576;
#pragma unroll
    for (int j = 0; j < 4; ++j)
      o[(size_t)(e0 + ty + j * 8) * 1024 + d0 + tx] = f2bf(tile[tx][ty + j * 8]);
  }
}

// ---------- XCD-aware bijective block swizzle (T1) ----------
// Dispatch order is x-fastest; block d lands on XCD d%8. Remap so each XCD
// owns a CONTIGUOUS run of logical tiles (consecutive x share the A-panel ->
// panel stays in that XCD's L2). Requires NWG % 8 == 0 (all our grids).

template <int GX, int GY, int GZ>
__device__ __forceinline__ void xcd_swz(int& bx, int& by, int& bz) {
  constexpr int NWG = GX * GY * GZ;
  static_assert(NWG % 8 == 0, "grid must be divisible by 8");
  constexpr int Q8 = NWG / 8;
  int flat = blockIdx.x + GX * (blockIdx.y + GY * blockIdx.z);
  flat = (flat & 7) * Q8 + (flat >> 3);
  bx = flat % GX;
  by = (flat / GX) % GY;
  bz = flat / (GX * GY);
}

// ================= 256x256 8-phase BT-GEMM =================
// Used ONLY where its grid is exactly tail-free at 1 block/CU (QK: 256
// blocks). For QKV (384 blocks -> 1.5 rounds at 1/CU) the legacy 128^2
// kernel at 2 blocks/CU is measurably faster (r0: 64.3 vs r8: 72.7 us).
// Stage ledger (verified r2/r4): P1 stages (t+1)A1->nxt.A1; P2 none;
// P3 (t+2)B0->cur.B0; P4 (t+2)B1->cur.B1 + (t+2)A0->cur.A0; vmcnt(6) at P4.

__device__ __forceinline__ void stage_half(const u16* __restrict__ g, int ld, int k0,
                                           u16* ldsb, int w, int l) {
  const int srow = l >> 3;                          // row within 8-row chunk
  const int scol = ((l & 7) ^ (srow & 7)) * 8;      // swizzled 16B chunk (u16 units)
#pragma unroll
  for (int q = 0; q < 2; ++q) {
    const int r = w * 16 + q * 8;                   // 8 waves x 2 x 8 rows = 128
    gld_lds16(g + (long)(r + srow) * ld + k0 + scol, (void*)(ldsb + r * 64));
  }
}

template <int EPI, int GX, int GY, int GZ>
__global__ __launch_bounds__(512, 2)
void gemm256_bt(const u16* __restrict__ A, const u16* __restrict__ B,
                void* __restrict__ Cv, int K, int lda, int ldb, int ldc,
                long sA, long sB, long sC,
                u16* __restrict__ auxK, u16* __restrict__ auxV) {
  __shared__ __align__(16) u16 lds[65536];          // 128 KiB

  const int t = threadIdx.x;
  const int w = t >> 6, l = t & 63;
  const int wm = w >> 2, wn = w & 3;
  const int lr = l & 15, lq = l >> 4;
  const int rsw = l & 7;                            // read-side swizzle key
  int bxs, bys, bz;
  xcd_swz<GX, GY, GZ>(bxs, bys, bz);
  const int m0 = bys * 256, n0 = bxs * 256;
  const u16* Ar = A + (long)bz * sA + (long)m0 * lda;
  const u16* Br = B + (long)bz * sB + (long)n0 * ldb;

  u16* curA = lds;
  u16* curB = lds + 16384;
  u16* nxtA = lds + 32768;
  u16* nxtB = lds + 49152;

  const int nt = K >> 6;

  f32x4 acc[8][4] = {};

  // ---- prologue: tile0 {A0,B0,B1,A1} -> cur; tile1 {A0,B0,B1} -> nxt ----
  stage_half(Ar,             lda, 0, curA,        w, l);
  stage_half(Br,             ldb, 0, curB,        w, l);
  stage_half(Br + 128 * ldb, ldb, 0, curB + 8192, w, l);
  stage_half(Ar + 128 * lda, lda, 0, curA + 8192, w, l);
  asm volatile("s_waitcnt vmcnt(4)" ::: "memory");
  if (nt > 1) {
    stage_half(Ar,             lda, 64, nxtA,        w, l);
    stage_half(Br,             ldb, 64, nxtB,        w, l);
    stage_half(Br + 128 * ldb, ldb, 64, nxtB + 8192, w, l);
    asm volatile("s_waitcnt vmcnt(6)" ::: "memory");   // tile0 fully landed
  } else {
    asm volatile("s_waitcnt vmcnt(0)" ::: "memory");
  }
  __builtin_amdgcn_s_barrier();

  for (int tt = 0; tt < nt; ++tt) {
    const int kc = tt << 6;
    bf16x8 a0[4][2], a1[4][2], b0[2][2], b1[2][2];

    // -------- phase 1: read A-half-lo(8) + B-quarter-0(4); stage (t+1)A1 ----
#pragma unroll
    for (int mi = 0; mi < 4; ++mi)
#pragma unroll
      for (int j = 0; j < 2; ++j)
        a0[mi][j] = *(const bf16x8*)(curA + (wm * 128 + mi * 16 + lr) * 64 +
                                     (((j * 4 + lq) ^ rsw) * 8));
#pragma unroll
    for (int ni = 0; ni < 2; ++ni)
#pragma unroll
      for (int j = 0; j < 2; ++j)
        b0[ni][j] = *(const bf16x8*)(curB + (wn * 64 + ni * 16 + lr) * 64 +
                                     (((j * 4 + lq) ^ rsw) * 8));
    if (tt + 1 < nt)
      stage_half(Ar + 128 * lda, lda, kc + 64, nxtA + 8192, w, l);
    __builtin_amdgcn_s_barrier();
    asm volatile("s_waitcnt lgkmcnt(0)" ::: "memory");
    __builtin_amdgcn_sched_barrier(0);
    __builtin_amdgcn_s_setprio(1);
#pragma unroll
    for (int mi = 0; mi < 4; ++mi)
#pragma unroll
      for (int ni = 0; ni < 2; ++ni)
#pragma unroll
        for (int j = 0; j < 2; ++j)
          acc[mi][ni] = __builtin_amdgcn_mfma_f32_16x16x32_bf16(a0[mi][j], b0[ni][j], acc[mi][ni], 0, 0, 0);
    __builtin_amdgcn_s_setprio(0);
    __builtin_amdgcn_s_barrier();

    // -------- phase 2: read B-quarter-1(4); no stage (cur.A live till P3) ---
#pragma unroll
    for (int ni = 0; ni < 2; ++ni)
#pragma unroll
      for (int j = 0; j < 2; ++j)
        b1[ni][j] = *(const bf16x8*)(curB + (wn * 64 + (ni + 2) * 16 + lr) * 64 +
                                     (((j * 4 + lq) ^ rsw) * 8));
    __builtin_amdgcn_s_barrier();
    asm volatile("s_waitcnt lgkmcnt(0)" ::: "memory");
    __builtin_amdgcn_sched_barrier(0);
    __builtin_amdgcn_s_setprio(1);
#pragma unroll
    for (int mi = 0; mi < 4; ++mi)
#pragma unroll
      for (int ni = 0; ni < 2; ++ni)
#pragma unroll
        for (int j = 0; j < 2; ++j)
          acc[mi][ni + 2] = __builtin_amdgcn_mfma_f32_16x16x32_bf16(a0[mi][j], b1[ni][j], acc[mi][ni + 2], 0, 0, 0);
    __builtin_amdgcn_s_setprio(0);
    __builtin_amdgcn_s_barrier();

    // -------- phase 3: read A-half-hi(8); stage (t+2)B0 ---------------------
#pragma unroll
    for (int mi = 0; mi < 4; ++mi)
#pragma unroll
      for (int j = 0; j < 2; ++j)
        a1[mi][j] = *(const bf16x8*)(curA + (wm * 128 + (mi + 4) * 16 + lr) * 64 +
                                     (((j * 4 + lq) ^ rsw) * 8));
    if (tt + 2 < nt)
      stage_half(Br, ldb, kc + 128, curB, w, l);
    __builtin_amdgcn_s_barrier();
    asm volatile("s_waitcnt lgkmcnt(0)" ::: "memory");
    __builtin_amdgcn_sched_barrier(0);
    __builtin_amdgcn_s_setprio(1);
#pragma unroll
    for (int mi = 0; mi < 4; ++mi)
#pragma unroll
      for (int ni = 0; ni < 2; ++ni)
#pragma unroll
        for (int j = 0; j < 2; ++j)
          acc[mi + 4][ni + 2] = __builtin_amdgcn_mfma_f32_16x16x32_bf16(a1[mi][j], b1[ni][j], acc[mi + 4][ni + 2], 0, 0, 0);
    __builtin_amdgcn_s_setprio(0);
    __builtin_amdgcn_s_barrier();

    // -------- phase 4: stage (t+2)B1 + (t+2)A0; MFMA hi,lo; tile-end vmcnt --
    if (tt + 2 < nt) {
      stage_half(Br + 128 * ldb, ldb, kc + 128, curB + 8192, w, l);
      stage_half(Ar,             lda, kc + 128, curA,        w, l);
    }
    __builtin_amdgcn_s_barrier();
    __builtin_amdgcn_sched_barrier(0);
    __builtin_amdgcn_s_setprio(1);
#pragma unroll
    for (int mi = 0; mi < 4; ++mi)
#pragma unroll
      for (int ni = 0; ni < 2; ++ni)
#pragma unroll
        for (int j = 0; j < 2; ++j)
          acc[mi + 4][ni] = __builtin_amdgcn_mfma_f32_16x16x32_bf16(a1[mi][j], b0[ni][j], acc[mi + 4][ni], 0, 0, 0);
    __builtin_amdgcn_s_setprio(0);
    if (tt + 2 < nt)      asm volatile("s_waitcnt vmcnt(6)" ::: "memory");
    else if (tt + 1 < nt) asm volatile("s_waitcnt vmcnt(0)" ::: "memory");
    __builtin_amdgcn_s_barrier();

    { u16* x_ = curA; curA = nxtA; nxtA = x_; }
    { u16* y_ = curB; curB = nxtB; nxtB = y_; }
  }

  // ======================= epilogues =======================
  if (EPI == EPI_QK) {
    // Pure exp+store. Rowsum is computed in the PV kernel (it reads the
    // whole P' row anyway) -> no atomics, no cross-block reduction here.
#pragma unroll
    for (int mi = 0; mi < 8; ++mi) {
#pragma unroll
      for (int i = 0; i < 4; ++i) {
        const int row = m0 + wm * 128 + mi * 16 + lq * 4 + i;
#pragma unroll
        for (int ni = 0; ni < 4; ++ni) {
          const int col = n0 + wn * 64 + ni * 16 + lr;
          const u16 h = f2bf(__expf(acc[mi][ni][i] * 0.03125f));  // unnorm prob
          ((u16*)Cv)[(long)bz * sC + (long)row * ldc + col] = h;
        }
      }
    }
    return;
  }

  // EPI_QKV dense (unused in current launch config; kept for completeness)
  u16* qkv_out = (n0 < 1024) ? (u16*)Cv : auxK;
  const int nl0 = n0 & 1023;
#pragma unroll
  for (int mi = 0; mi < 8; ++mi) {
#pragma unroll
    for (int i = 0; i < 4; ++i) {
      const int row = m0 + wm * 128 + mi * 16 + lq * 4 + i;
#pragma unroll
      for (int ni = 0; ni < 4; ++ni)
        qkv_out[(long)row * 1024 + nl0 + wn * 64 + ni * 16 + lr] = f2bf(acc[mi][ni][i]);
    }
  }
  (void)auxV;
}

// ---------- legacy 128x128 BT-GEMM (QKV + PV) ----------
// 4 waves, 34 KiB max LDS -> 2 blocks/CU. QKV grid 24x64 = 1536 = 6/CU,
// tail-free (measured 64.3 us in r0 / 65.7 in r9 vs 72.7 for the 256^2
// variant). The 2-blocks/CU inter-block slip (one block computes while the
// other stages) is the throughput mechanism here — r10's fused lockstep
// destroyed it (4x slowdown), so these stay separate kernels.
// EPI_QKV: n0<2048 dense Q/K stores; n0>=2048 V-transpose through LDS -> VT.
// EPI_PV: self-computes rowsum from its A-fragments (reads full P' row).

template <int EPI, int GX, int GY, int GZ>
__global__ __launch_bounds__(256)
void gemm_bt(const u16* __restrict__ A, const u16* __restrict__ B,
             void* __restrict__ Cv, int K, int lda, int ldb, int ldc,
             long sA, long sB, long sC,
             u16* __restrict__ auxK, u16* __restrict__ auxV) {
  constexpr int LDS_U16 = (EPI == EPI_QKV) ? (128 * 136) : (128 * 128);
  __shared__ __align__(16) u16 lds[LDS_U16];
  u16* As = lds;
  u16* Bs = lds + 128 * 64;

  const int t = threadIdx.x;
  const int w = t >> 6, l = t & 63;
  int bxs, bys, bz;
  xcd_swz<GX, GY, GZ>(bxs, bys, bz);
  const u16* Ab = A + (long)bz * sA;
  const u16* Bb = B + (long)bz * sB;
  const int m0 = bys * 128, n0 = bxs * 128;
  const int wm = w & 1, wn = w >> 1;
  const int lr = l & 15, lq = l >> 4;
  const int srow = l >> 3;
  const int scol = ((l & 7) ^ ((l >> 3) & 7)) * 8;
  const int rsw = l & 7;

  f32x4 acc[4][4] = {};
  float rsp[4] = {0.f, 0.f, 0.f, 0.f};   // EPI_PV: per-lane partial rowsums

  for (int k0 = 0; k0 < K; k0 += 64) {
    __syncthreads();
#pragma unroll
    for (int c = 0; c < 4; ++c) {
      const int rb = (w * 4 + c) * 8;
      gld_lds16(Ab + (long)(m0 + rb + srow) * lda + k0 + scol, (void*)(As + rb * 64));
      gld_lds16(Bb + (long)(n0 + rb + srow) * ldb + k0 + scol, (void*)(Bs + rb * 64));
    }
    __syncthreads();
#pragma unroll
    for (int j = 0; j < 2; ++j) {
      bf16x8 af[4], bfr[4];
#pragma unroll
      for (int i = 0; i < 4; ++i) {
        const int ch = ((j * 4 + lq) ^ rsw) * 8;
        af[i]  = *(const bf16x8*)(As + (wm * 64 + i * 16 + lr) * 64 + ch);
        bfr[i] = *(const bf16x8*)(Bs + (wn * 64 + i * 16 + lr) * 64 + ch);
      }
      if (EPI == EPI_PV) {
        // af[i] holds 8 k-elems of A-row (wm*64 + i*16 + lr); accumulate.
#pragma unroll
        for (int i = 0; i < 4; ++i)
#pragma unroll
          for (int e = 0; e < 8; ++e)
            rsp[i] += (float)af[i][e];
      }
#pragma unroll
      for (int mi = 0; mi < 4; ++mi)
#pragma unroll
        for (int ni = 0; ni < 4; ++ni)
          acc[mi][ni] = __builtin_amdgcn_mfma_f32_16x16x32_bf16(af[mi], bfr[ni], acc[mi][ni], 0, 0, 0);
    }
  }

  if (EPI == EPI_PV) {
    // reduce over the 4 lq lanes -> every lane holds the full rowsum of
    // A-row (wm*64 + i*16 + lr)
#pragma unroll
    for (int i = 0; i < 4; ++i) {
      rsp[i] += __shfl_xor(rsp[i], 16, 64);
      rsp[i] += __shfl_xor(rsp[i], 32, 64);
    }
  }

  if (EPI == EPI_QKV && n0 >= 2048) {
    // ---- V slice: transpose 128x128 tile through LDS, coalesced 16B stores ----
    u16* tp = lds;  // [128 cols][136 rows-padded] u16 = 34816 B
    __syncthreads();  // all frag reads done; safe to overwrite As/Bs
#pragma unroll
    for (int mi = 0; mi < 4; ++mi) {
      const int row0 = wm * 64 + mi * 16 + lq * 4;
#pragma unroll
      for (int ni = 0; ni < 4; ++ni) {
        const int col = wn * 64 + ni * 16 + lr;
        u16x4 v4;
#pragma unroll
        for (int i = 0; i < 4; ++i) v4[i] = f2bf(acc[mi][ni][i]);
        *(u16x4*)(tp + col * 136 + row0) = v4;   // 8B store, 8B-aligned
      }
    }
    __syncthreads();
    const int e0 = n0 - 2048;
    const long bb = m0 >> 11;           // batch
    const int kbase = m0 & 2047;
    u16* vt_base = auxV + bb * 2097152;
#pragma unroll
    for (int q = 0; q < 8; ++q) {
      const int chunk = q * 256 + t;
      const int c = chunk >> 4, r0 = (chunk & 15) * 8;
      u16x8 v = *(const u16x8*)(tp + c * 136 + r0);      // b128, conflict-free
      *(u16x8*)(vt_base + (long)(e0 + c) * 2048 + kbase + r0) = v;  // coalesced
    }
    return;
  }

  u16* qkv_out = nullptr;
  int nl0 = 0;
  if (EPI == EPI_QKV) {
    qkv_out = (n0 < 1024) ? (u16*)Cv : auxK;
    nl0 = n0 & 1023;
  }

#pragma unroll
  for (int mi = 0; mi < 4; ++mi) {
#pragma unroll
    for (int i = 0; i < 4; ++i) {
      const int row = m0 + wm * 64 + mi * 16 + lq * 4 + i;
      float inv;
      if (EPI == EPI_PV) {
        // C-row (mi*16 + lq*4 + i) as A-frag coords: index mi, lr' = lq*4+i.
        const float rstot = __shfl(rsp[mi], lq * 4 + i, 64);
        inv = 1.0f / rstot;
      }
#pragma unroll
      for (int ni = 0; ni < 4; ++ni) {
        const float val = acc[mi][ni][i];
        const int col = n0 + wn * 64 + ni * 16 + lr;
        if (EPI == EPI_QKV) {
          qkv_out[(long)row * 1024 + nl0 + wn * 64 + ni * 16 + lr] = f2bf(val);
        } else if (EPI == EPI_QK) {
          const u16 h = f2bf(__expf(val * 0.03125f));
          ((u16*)Cv)[(long)bz * sC + (long)row * ldc + col] = h;
        } else {  // EPI_PV
          ((float*)Cv)[(long)bz * sC + (long)row * ldc + col] = val * inv;
        }
      }
    }
  }
}

// ---------- launch ----------

extern "C" void kernel_launch(void* const* d_in, const int* in_sizes, int n_in,
                              void* d_out, int out_size, void* d_ws, size_t ws_size,
                              hipStream_t stream) {
  (void)in_sizes; (void)n_in; (void)out_size;
  const float* x    = (const float*)d_in[0];
  const float* kern = (const float*)d_in[1];
  float* out = (float*)d_out;
  char* ws = (char*)d_ws;
  const size_t MB = 1024 * 1024;
  u16*   xbf  = (u16*)(ws);              // 16 MB: [8192][1024] bf16
  u16*   WT   = (u16*)(ws + 16 * MB);    //  6 MB: [3][1024][1024] bf16
  u16*   Qc   = (u16*)(ws + 22 * MB);    // 16 MB: [8192][1024] bf16
  u16*   Kc   = (u16*)(ws + 38 * MB);    // 16 MB: [8192][1024] bf16
  u16*   VT   = (u16*)(ws + 54 * MB);    // 16 MB: [4][1024e][2048k] bf16
  u16*   SP   = (u16*)(ws + 70 * MB);    // 32 MB: [4][2048][2048] bf16 unnormalized probs
  if (ws_size < 102 * MB)
    fprintf(stderr, "WARNING: ws_size %zu too small\n", ws_size);

  prep_kernel<<<7168, 256, 0, stream>>>(x, xbf, kern, WT);
  // QKV: M=8192, N=3072 (Q|K|V), K=1024; legacy 128^2: 1536 blocks = 6/CU
  // tail-free (measured faster than 256^2's 384-block 1.5-round grid).
  // V slice transposed in-epilogue into VT.
  gemm_bt<EPI_QKV, 24, 64, 1><<<dim3(24, 64, 1), 256, 0, stream>>>(
      xbf, WT, Qc, 1024, 1024, 1024, 1024, 0, 0, 0, Kc, VT);
  // P'[b][q][k] = exp((Q[b][q,:].K[b][k,:])/32); 256^2: 256 blocks = 1/CU
  gemm256_bt<EPI_QK, 8, 8, 4><<<dim3(8, 8, 4), 512, 0, stream>>>(
      Qc, Kc, SP, 1024, 1024, 1024, 2048,
      2048L * 1024, 2048L * 1024, 2048L * 2048, nullptr, nullptr);
  // out[b][q][e] = (P'[b][q,:] . VT[b][e,:]) / rowsum(P'[b][q,:])  (self-computed)
  gemm_bt<EPI_PV, 8, 16, 4><<<dim3(8, 16, 4), 256, 0, stream>>>(
      SP, VT, out, 2048, 2048, 2048, 1024,
      2048L * 2048, 1024L * 2048, 2048L * 1024, nullptr, nullptr);
}

// Round 12
// 232.335 us; speedup vs baseline: 2.8816x; 1.0186x over previous
//
#include <hip/hip_runtime.h>
#include <hip/hip_bf16.h>
#include <cstdio>

typedef __bf16  bf16x8 __attribute__((ext_vector_type(8)));
typedef float   f32x4  __attribute__((ext_vector_type(4)));
typedef unsigned short u16;
typedef u16     u16x8  __attribute__((ext_vector_type(8)));
typedef u16     u16x4  __attribute__((ext_vector_type(4)));

// ---------- helpers ----------

__device__ __forceinline__ void gld_lds16(const void* g, void* l) {
  // async global->LDS, 16B per lane; LDS dest is wave-uniform base + lane*16
  __builtin_amdgcn_global_load_lds(
      (const __attribute__((address_space(1))) unsigned int*)g,
      (__attribute__((address_space(3))) unsigned int*)l,
      16, 0, 0);
}

__device__ __forceinline__ u16 f2bf(float f) {
  union { float f; unsigned int u; } c{f};
  unsigned int u = c.u;
  u += 0x7fffu + ((u >> 16) & 1u);   // round-to-nearest-even
  return (u16)(u >> 16);
}

__device__ __forceinline__ float bf2f(u16 h) {
  union { unsigned int u; float f; } c{(unsigned int)h << 16};
  return c.f;
}

enum { EPI_QKV = 0, EPI_QK = 1, EPI_PV = 2 };

// ---------- prep: cast x -> bf16, pack/transpose weights ----------
// grid: [0,4096) cast blocks, [4096,7168) weight tiles

__global__ __launch_bounds__(256) void prep_kernel(const float* __restrict__ x,
                                                   u16* __restrict__ xbf,
                                                   const float* __restrict__ w,
                                                   u16* __restrict__ wt) {
  __shared__ float tile[32][33];
  const int bid = blockIdx.x;
  if (bid < 4096) {
    const int i = (bid * 256 + threadIdx.x) * 8;
    float4 a = *(const float4*)(x + i);
    float4 b = *(const float4*)(x + i + 4);
    u16x8 r;
    r[0] = f2bf(a.x); r[1] = f2bf(a.y); r[2] = f2bf(a.z); r[3] = f2bf(a.w);
    r[4] = f2bf(b.x); r[5] = f2bf(b.y); r[6] = f2bf(b.z); r[7] = f2bf(b.w);
    *(u16x8*)(xbf + i) = r;
  } else {
    // WT[s][e][d] = w[s][d][e], s in 0..2
    const int b2 = bid - 4096;
    const int s = b2 >> 10, r = b2 & 1023;
    const int e0 = (r & 31) * 32, d0 = (r >> 5) * 32;
    const int tx = threadIdx.x & 31, ty = threadIdx.x >> 5;
    const float* in = w + (size_t)s * 1048576;
#pragma unroll
    for (int j = 0; j < 4; ++j)
      tile[ty + j * 8][tx] = in[(size_t)(d0 + ty + j * 8) * 1024 + e0 + tx];
    __syncthreads();
    u16* o = wt + (size_t)s * 1048576;
#pragma unroll
    for (int j = 0; j < 4; ++j)
      o[(size_t)(e0 + ty + j * 8) * 1024 + d0 + tx] = f2bf(tile[tx][ty + j * 8]);
  }
}

// ---------- XCD-aware bijective block swizzle (T1) ----------
// Remaps so each XCD owns a CONTIGUOUS run of logical tiles. WINS when the
// per-XCD working set then fits its 4 MiB L2 (gemm256 grids: r4 FETCH
// 79->59.5 MB). LOSES when contiguity makes each XCD touch the ENTIRE
// B operand (legacy QKV 24x64 grid: all 6 MB of WT per XCD -> L2 thrash;
// measured r0 unswz 64.3us/FETCH 71.9MB vs r9/r11 swz 67.3us/83.8MB).
// Hence the SWZ switch: per-launch choice, evidence-based.

template <int GX, int GY, int GZ, bool EN>
__device__ __forceinline__ void xcd_swz(int& bx, int& by, int& bz) {
  constexpr int NWG = GX * GY * GZ;
  static_assert(NWG % 8 == 0, "grid must be divisible by 8");
  constexpr int Q8 = NWG / 8;
  int flat = blockIdx.x + GX * (blockIdx.y + GY * blockIdx.z);
  if (EN) flat = (flat & 7) * Q8 + (flat >> 3);
  bx = flat % GX;
  by = (flat / GX) % GY;
  bz = flat / (GX * GY);
}

// ================= 256x256 8-phase BT-GEMM =================
// Used ONLY where its grid is exactly tail-free at 1 block/CU (QK: 256
// blocks). For QKV (384 blocks -> 1.5 rounds at 1/CU) the legacy 128^2
// kernel at 2 blocks/CU is measurably faster (r0: 64.3 vs r8: 72.7 us).
// Stage ledger (verified r2/r4): P1 stages (t+1)A1->nxt.A1; P2 none;
// P3 (t+2)B0->cur.B0; P4 (t+2)B1->cur.B1 + (t+2)A0->cur.A0; vmcnt(6) at P4.

__device__ __forceinline__ void stage_half(const u16* __restrict__ g, int ld, int k0,
                                           u16* ldsb, int w, int l) {
  const int srow = l >> 3;                          // row within 8-row chunk
  const int scol = ((l & 7) ^ (srow & 7)) * 8;      // swizzled 16B chunk (u16 units)
#pragma unroll
  for (int q = 0; q < 2; ++q) {
    const int r = w * 16 + q * 8;                   // 8 waves x 2 x 8 rows = 128
    gld_lds16(g + (long)(r + srow) * ld + k0 + scol, (void*)(ldsb + r * 64));
  }
}

template <int EPI, int GX, int GY, int GZ>
__global__ __launch_bounds__(512, 2)
void gemm256_bt(const u16* __restrict__ A, const u16* __restrict__ B,
                void* __restrict__ Cv, int K, int lda, int ldb, int ldc,
                long sA, long sB, long sC,
                u16* __restrict__ auxK, u16* __restrict__ auxV) {
  __shared__ __align__(16) u16 lds[65536];          // 128 KiB

  const int t = threadIdx.x;
  const int w = t >> 6, l = t & 63;
  const int wm = w >> 2, wn = w & 3;
  const int lr = l & 15, lq = l >> 4;
  const int rsw = l & 7;                            // read-side swizzle key
  int bxs, bys, bz;
  xcd_swz<GX, GY, GZ, true>(bxs, bys, bz);
  const int m0 = bys * 256, n0 = bxs * 256;
  const u16* Ar = A + (long)bz * sA + (long)m0 * lda;
  const u16* Br = B + (long)bz * sB + (long)n0 * ldb;

  u16* curA = lds;
  u16* curB = lds + 16384;
  u16* nxtA = lds + 32768;
  u16* nxtB = lds + 49152;

  const int nt = K >> 6;

  f32x4 acc[8][4] = {};

  // ---- prologue: tile0 {A0,B0,B1,A1} -> cur; tile1 {A0,B0,B1} -> nxt ----
  stage_half(Ar,             lda, 0, curA,        w, l);
  stage_half(Br,             ldb, 0, curB,        w, l);
  stage_half(Br + 128 * ldb, ldb, 0, curB + 8192, w, l);
  stage_half(Ar + 128 * lda, lda, 0, curA + 8192, w, l);
  asm volatile("s_waitcnt vmcnt(4)" ::: "memory");
  if (nt > 1) {
    stage_half(Ar,             lda, 64, nxtA,        w, l);
    stage_half(Br,             ldb, 64, nxtB,        w, l);
    stage_half(Br + 128 * ldb, ldb, 64, nxtB + 8192, w, l);
    asm volatile("s_waitcnt vmcnt(6)" ::: "memory");   // tile0 fully landed
  } else {
    asm volatile("s_waitcnt vmcnt(0)" ::: "memory");
  }
  __builtin_amdgcn_s_barrier();

  for (int tt = 0; tt < nt; ++tt) {
    const int kc = tt << 6;
    bf16x8 a0[4][2], a1[4][2], b0[2][2], b1[2][2];

    // -------- phase 1: read A-half-lo(8) + B-quarter-0(4); stage (t+1)A1 ----
#pragma unroll
    for (int mi = 0; mi < 4; ++mi)
#pragma unroll
      for (int j = 0; j < 2; ++j)
        a0[mi][j] = *(const bf16x8*)(curA + (wm * 128 + mi * 16 + lr) * 64 +
                                     (((j * 4 + lq) ^ rsw) * 8));
#pragma unroll
    for (int ni = 0; ni < 2; ++ni)
#pragma unroll
      for (int j = 0; j < 2; ++j)
        b0[ni][j] = *(const bf16x8*)(curB + (wn * 64 + ni * 16 + lr) * 64 +
                                     (((j * 4 + lq) ^ rsw) * 8));
    if (tt + 1 < nt)
      stage_half(Ar + 128 * lda, lda, kc + 64, nxtA + 8192, w, l);
    __builtin_amdgcn_s_barrier();
    asm volatile("s_waitcnt lgkmcnt(0)" ::: "memory");
    __builtin_amdgcn_sched_barrier(0);
    __builtin_amdgcn_s_setprio(1);
#pragma unroll
    for (int mi = 0; mi < 4; ++mi)
#pragma unroll
      for (int ni = 0; ni < 2; ++ni)
#pragma unroll
        for (int j = 0; j < 2; ++j)
          acc[mi][ni] = __builtin_amdgcn_mfma_f32_16x16x32_bf16(a0[mi][j], b0[ni][j], acc[mi][ni], 0, 0, 0);
    __builtin_amdgcn_s_setprio(0);
    __builtin_amdgcn_s_barrier();

    // -------- phase 2: read B-quarter-1(4); no stage (cur.A live till P3) ---
#pragma unroll
    for (int ni = 0; ni < 2; ++ni)
#pragma unroll
      for (int j = 0; j < 2; ++j)
        b1[ni][j] = *(const bf16x8*)(curB + (wn * 64 + (ni + 2) * 16 + lr) * 64 +
                                     (((j * 4 + lq) ^ rsw) * 8));
    __builtin_amdgcn_s_barrier();
    asm volatile("s_waitcnt lgkmcnt(0)" ::: "memory");
    __builtin_amdgcn_sched_barrier(0);
    __builtin_amdgcn_s_setprio(1);
#pragma unroll
    for (int mi = 0; mi < 4; ++mi)
#pragma unroll
      for (int ni = 0; ni < 2; ++ni)
#pragma unroll
        for (int j = 0; j < 2; ++j)
          acc[mi][ni + 2] = __builtin_amdgcn_mfma_f32_16x16x32_bf16(a0[mi][j], b1[ni][j], acc[mi][ni + 2], 0, 0, 0);
    __builtin_amdgcn_s_setprio(0);
    __builtin_amdgcn_s_barrier();

    // -------- phase 3: read A-half-hi(8); stage (t+2)B0 ---------------------
#pragma unroll
    for (int mi = 0; mi < 4; ++mi)
#pragma unroll
      for (int j = 0; j < 2; ++j)
        a1[mi][j] = *(const bf16x8*)(curA + (wm * 128 + (mi + 4) * 16 + lr) * 64 +
                                     (((j * 4 + lq) ^ rsw) * 8));
    if (tt + 2 < nt)
      stage_half(Br, ldb, kc + 128, curB, w, l);
    __builtin_amdgcn_s_barrier();
    asm volatile("s_waitcnt lgkmcnt(0)" ::: "memory");
    __builtin_amdgcn_sched_barrier(0);
    __builtin_amdgcn_s_setprio(1);
#pragma unroll
    for (int mi = 0; mi < 4; ++mi)
#pragma unroll
      for (int ni = 0; ni < 2; ++ni)
#pragma unroll
        for (int j = 0; j < 2; ++j)
          acc[mi + 4][ni + 2] = __builtin_amdgcn_mfma_f32_16x16x32_bf16(a1[mi][j], b1[ni][j], acc[mi + 4][ni + 2], 0, 0, 0);
    __builtin_amdgcn_s_setprio(0);
    __builtin_amdgcn_s_barrier();

    // -------- phase 4: stage (t+2)B1 + (t+2)A0; MFMA hi,lo; tile-end vmcnt --
    if (tt + 2 < nt) {
      stage_half(Br + 128 * ldb, ldb, kc + 128, curB + 8192, w, l);
      stage_half(Ar,             lda, kc + 128, curA,        w, l);
    }
    __builtin_amdgcn_s_barrier();
    __builtin_amdgcn_sched_barrier(0);
    __builtin_amdgcn_s_setprio(1);
#pragma unroll
    for (int mi = 0; mi < 4; ++mi)
#pragma unroll
      for (int ni = 0; ni < 2; ++ni)
#pragma unroll
        for (int j = 0; j < 2; ++j)
          acc[mi + 4][ni] = __builtin_amdgcn_mfma_f32_16x16x32_bf16(a1[mi][j], b0[ni][j], acc[mi + 4][ni], 0, 0, 0);
    __builtin_amdgcn_s_setprio(0);
    if (tt + 2 < nt)      asm volatile("s_waitcnt vmcnt(6)" ::: "memory");
    else if (tt + 1 < nt) asm volatile("s_waitcnt vmcnt(0)" ::: "memory");
    __builtin_amdgcn_s_barrier();

    { u16* x_ = curA; curA = nxtA; nxtA = x_; }
    { u16* y_ = curB; curB = nxtB; nxtB = y_; }
  }

  // ======================= epilogues =======================
  if (EPI == EPI_QK) {
    // Pure exp+store. Rowsum is computed in the PV kernel (it reads the
    // whole P' row anyway) -> no atomics, no cross-block reduction here.
#pragma unroll
    for (int mi = 0; mi < 8; ++mi) {
#pragma unroll
      for (int i = 0; i < 4; ++i) {
        const int row = m0 + wm * 128 + mi * 16 + lq * 4 + i;
#pragma unroll
        for (int ni = 0; ni < 4; ++ni) {
          const int col = n0 + wn * 64 + ni * 16 + lr;
          const u16 h = f2bf(__expf(acc[mi][ni][i] * 0.03125f));  // unnorm prob
          ((u16*)Cv)[(long)bz * sC + (long)row * ldc + col] = h;
        }
      }
    }
    return;
  }

  // EPI_QKV dense (unused in current launch config; kept for completeness)
  u16* qkv_out = (n0 < 1024) ? (u16*)Cv : auxK;
  const int nl0 = n0 & 1023;
#pragma unroll
  for (int mi = 0; mi < 8; ++mi) {
#pragma unroll
    for (int i = 0; i < 4; ++i) {
      const int row = m0 + wm * 128 + mi * 16 + lq * 4 + i;
#pragma unroll
      for (int ni = 0; ni < 4; ++ni)
        qkv_out[(long)row * 1024 + nl0 + wn * 64 + ni * 16 + lr] = f2bf(acc[mi][ni][i]);
    }
  }
  (void)auxV;
}

// ---------- legacy 128x128 BT-GEMM (QKV + PV) ----------
// 4 waves, 34 KiB max LDS -> 2 blocks/CU. QKV grid 24x64 = 1536 = 6/CU,
// tail-free. The 2-blocks/CU inter-block slip (one block computes while the
// other stages) is the throughput mechanism here — r10's fused lockstep
// destroyed it (4x slowdown), so these stay separate kernels.
// SWZ=0 for QKV: contiguous-XCD mapping forces all 6 MB of WT through each
// XCD's 4 MiB L2 (r9/r11: 67.3us/FETCH 83.8MB); round-robin keeps only ~3
// B-panels per XCD hot (r0: 64.3us/71.9MB). PV keeps SWZ=1 (its measured
// config, r6: 48.6-50us).
// EPI_QKV: n0<2048 dense Q/K stores; n0>=2048 V-transpose through LDS -> VT.
// EPI_PV: self-computes rowsum from its A-fragments (reads full P' row).

template <int EPI, int GX, int GY, int GZ, bool SWZ>
__global__ __launch_bounds__(256)
void gemm_bt(const u16* __restrict__ A, const u16* __restrict__ B,
             void* __restrict__ Cv, int K, int lda, int ldb, int ldc,
             long sA, long sB, long sC,
             u16* __restrict__ auxK, u16* __restrict__ auxV) {
  constexpr int LDS_U16 = (EPI == EPI_QKV) ? (128 * 136) : (128 * 128);
  __shared__ __align__(16) u16 lds[LDS_U16];
  u16* As = lds;
  u16* Bs = lds + 128 * 64;

  const int t = threadIdx.x;
  const int w = t >> 6, l = t & 63;
  int bxs, bys, bz;
  xcd_swz<GX, GY, GZ, SWZ>(bxs, bys, bz);
  const u16* Ab = A + (long)bz * sA;
  const u16* Bb = B + (long)bz * sB;
  const int m0 = bys * 128, n0 = bxs * 128;
  const int wm = w & 1, wn = w >> 1;
  const int lr = l & 15, lq = l >> 4;
  const int srow = l >> 3;
  const int scol = ((l & 7) ^ ((l >> 3) & 7)) * 8;
  const int rsw = l & 7;

  f32x4 acc[4][4] = {};
  float rsp[4] = {0.f, 0.f, 0.f, 0.f};   // EPI_PV: per-lane partial rowsums

  for (int k0 = 0; k0 < K; k0 += 64) {
    __syncthreads();
#pragma unroll
    for (int c = 0; c < 4; ++c) {
      const int rb = (w * 4 + c) * 8;
      gld_lds16(Ab + (long)(m0 + rb + srow) * lda + k0 + scol, (void*)(As + rb * 64));
      gld_lds16(Bb + (long)(n0 + rb + srow) * ldb + k0 + scol, (void*)(Bs + rb * 64));
    }
    __syncthreads();
#pragma unroll
    for (int j = 0; j < 2; ++j) {
      bf16x8 af[4], bfr[4];
#pragma unroll
      for (int i = 0; i < 4; ++i) {
        const int ch = ((j * 4 + lq) ^ rsw) * 8;
        af[i]  = *(const bf16x8*)(As + (wm * 64 + i * 16 + lr) * 64 + ch);
        bfr[i] = *(const bf16x8*)(Bs + (wn * 64 + i * 16 + lr) * 64 + ch);
      }
      if (EPI == EPI_PV) {
        // af[i] holds 8 k-elems of A-row (wm*64 + i*16 + lr); accumulate.
#pragma unroll
        for (int i = 0; i < 4; ++i)
#pragma unroll
          for (int e = 0; e < 8; ++e)
            rsp[i] += (float)af[i][e];
      }
#pragma unroll
      for (int mi = 0; mi < 4; ++mi)
#pragma unroll
        for (int ni = 0; ni < 4; ++ni)
          acc[mi][ni] = __builtin_amdgcn_mfma_f32_16x16x32_bf16(af[mi], bfr[ni], acc[mi][ni], 0, 0, 0);
    }
  }

  if (EPI == EPI_PV) {
    // reduce over the 4 lq lanes -> every lane holds the full rowsum of
    // A-row (wm*64 + i*16 + lr)
#pragma unroll
    for (int i = 0; i < 4; ++i) {
      rsp[i] += __shfl_xor(rsp[i], 16, 64);
      rsp[i] += __shfl_xor(rsp[i], 32, 64);
    }
  }

  if (EPI == EPI_QKV && n0 >= 2048) {
    // ---- V slice: transpose 128x128 tile through LDS, coalesced 16B stores ----
    u16* tp = lds;  // [128 cols][136 rows-padded] u16 = 34816 B
    __syncthreads();  // all frag reads done; safe to overwrite As/Bs
#pragma unroll
    for (int mi = 0; mi < 4; ++mi) {
      const int row0 = wm * 64 + mi * 16 + lq * 4;
#pragma unroll
      for (int ni = 0; ni < 4; ++ni) {
        const int col = wn * 64 + ni * 16 + lr;
        u16x4 v4;
#pragma unroll
        for (int i = 0; i < 4; ++i) v4[i] = f2bf(acc[mi][ni][i]);
        *(u16x4*)(tp + col * 136 + row0) = v4;   // 8B store, 8B-aligned
      }
    }
    __syncthreads();
    const int e0 = n0 - 2048;
    const long bb = m0 >> 11;           // batch
    const int kbase = m0 & 2047;
    u16* vt_base = auxV + bb * 2097152;
#pragma unroll
    for (int q = 0; q < 8; ++q) {
      const int chunk = q * 256 + t;
      const int c = chunk >> 4, r0 = (chunk & 15) * 8;
      u16x8 v = *(const u16x8*)(tp + c * 136 + r0);      // b128, conflict-free
      *(u16x8*)(vt_base + (long)(e0 + c) * 2048 + kbase + r0) = v;  // coalesced
    }
    return;
  }

  u16* qkv_out = nullptr;
  int nl0 = 0;
  if (EPI == EPI_QKV) {
    qkv_out = (n0 < 1024) ? (u16*)Cv : auxK;
    nl0 = n0 & 1023;
  }

#pragma unroll
  for (int mi = 0; mi < 4; ++mi) {
#pragma unroll
    for (int i = 0; i < 4; ++i) {
      const int row = m0 + wm * 64 + mi * 16 + lq * 4 + i;
      float inv;
      if (EPI == EPI_PV) {
        // C-row (mi*16 + lq*4 + i) as A-frag coords: index mi, lr' = lq*4+i.
        const float rstot = __shfl(rsp[mi], lq * 4 + i, 64);
        inv = 1.0f / rstot;
      }
#pragma unroll
      for (int ni = 0; ni < 4; ++ni) {
        const float val = acc[mi][ni][i];
        const int col = n0 + wn * 64 + ni * 16 + lr;
        if (EPI == EPI_QKV) {
          qkv_out[(long)row * 1024 + nl0 + wn * 64 + ni * 16 + lr] = f2bf(val);
        } else if (EPI == EPI_QK) {
          const u16 h = f2bf(__expf(val * 0.03125f));
          ((u16*)Cv)[(long)bz * sC + (long)row * ldc + col] = h;
        } else {  // EPI_PV
          ((float*)Cv)[(long)bz * sC + (long)row * ldc + col] = val * inv;
        }
      }
    }
  }
}

// ---------- launch ----------

extern "C" void kernel_launch(void* const* d_in, const int* in_sizes, int n_in,
                              void* d_out, int out_size, void* d_ws, size_t ws_size,
                              hipStream_t stream) {
  (void)in_sizes; (void)n_in; (void)out_size;
  const float* x    = (const float*)d_in[0];
  const float* kern = (const float*)d_in[1];
  float* out = (float*)d_out;
  char* ws = (char*)d_ws;
  const size_t MB = 1024 * 1024;
  u16*   xbf  = (u16*)(ws);              // 16 MB: [8192][1024] bf16
  u16*   WT   = (u16*)(ws + 16 * MB);    //  6 MB: [3][1024][1024] bf16
  u16*   Qc   = (u16*)(ws + 22 * MB);    // 16 MB: [8192][1024] bf16
  u16*   Kc   = (u16*)(ws + 38 * MB);    // 16 MB: [8192][1024] bf16
  u16*   VT   = (u16*)(ws + 54 * MB);    // 16 MB: [4][1024e][2048k] bf16
  u16*   SP   = (u16*)(ws + 70 * MB);    // 32 MB: [4][2048][2048] bf16 unnormalized probs
  if (ws_size < 102 * MB)
    fprintf(stderr, "WARNING: ws_size %zu too small\n", ws_size);

  prep_kernel<<<7168, 256, 0, stream>>>(x, xbf, kern, WT);
  // QKV: M=8192, N=3072 (Q|K|V), K=1024; legacy 128^2: 1536 blocks = 6/CU
  // tail-free. SWZ=0: round-robin XCD mapping keeps per-XCD B working set
  // inside L2 (r0 A/B evidence: 64.3us/71.9MB vs swizzled 67.3us/83.8MB).
  gemm_bt<EPI_QKV, 24, 64, 1, false><<<dim3(24, 64, 1), 256, 0, stream>>>(
      xbf, WT, Qc, 1024, 1024, 1024, 1024, 0, 0, 0, Kc, VT);
  // P'[b][q][k] = exp((Q[b][q,:].K[b][k,:])/32); 256^2: 256 blocks = 1/CU
  gemm256_bt<EPI_QK, 8, 8, 4><<<dim3(8, 8, 4), 512, 0, stream>>>(
      Qc, Kc, SP, 1024, 1024, 1024, 2048,
      2048L * 1024, 2048L * 1024, 2048L * 2048, nullptr, nullptr);
  // out[b][q][e] = (P'[b][q,:] . VT[b][e,:]) / rowsum(P'[b][q,:])  (self-computed)
  gemm_bt<EPI_PV, 8, 16, 4, true><<<dim3(8, 16, 4), 256, 0, stream>>>(
      SP, VT, out, 2048, 2048, 2048, 1024,
      2048L * 2048, 1024L * 2048, 2048L * 1024, nullptr, nullptr);
}

// Round 13
// 228.079 us; speedup vs baseline: 2.9353x; 1.0187x over previous
//
#include <hip/hip_runtime.h>
#include <hip/hip_bf16.h>
#include <cstdio>

typedef __bf16  bf16x8 __attribute__((ext_vector_type(8)));
typedef float   f32x4  __attribute__((ext_vector_type(4)));
typedef unsigned short u16;
typedef u16     u16x8  __attribute__((ext_vector_type(8)));
typedef u16     u16x4  __attribute__((ext_vector_type(4)));

// ---------- helpers ----------

__device__ __forceinline__ void gld_lds16(const void* g, void* l) {
  // async global->LDS, 16B per lane; LDS dest is wave-uniform base + lane*16
  __builtin_amdgcn_global_load_lds(
      (const __attribute__((address_space(1))) unsigned int*)g,
      (__attribute__((address_space(3))) unsigned int*)l,
      16, 0, 0);
}

__device__ __forceinline__ u16 f2bf(float f) {
  union { float f; unsigned int u; } c{f};
  unsigned int u = c.u;
  u += 0x7fffu + ((u >> 16) & 1u);   // round-to-nearest-even
  return (u16)(u >> 16);
}

__device__ __forceinline__ float bf2f(u16 h) {
  union { unsigned int u; float f; } c{(unsigned int)h << 16};
  return c.f;
}

enum { EPI_QKV = 0, EPI_QK = 1, EPI_PV = 2 };

// ---------- prep: cast x -> bf16, pack/transpose weights ----------
// grid: [0,4096) cast blocks, [4096,7168) weight tiles

__global__ __launch_bounds__(256) void prep_kernel(const float* __restrict__ x,
                                                   u16* __restrict__ xbf,
                                                   const float* __restrict__ w,
                                                   u16* __restrict__ wt) {
  __shared__ float tile[32][33];
  const int bid = blockIdx.x;
  if (bid < 4096) {
    const int i = (bid * 256 + threadIdx.x) * 8;
    float4 a = *(const float4*)(x + i);
    float4 b = *(const float4*)(x + i + 4);
    u16x8 r;
    r[0] = f2bf(a.x); r[1] = f2bf(a.y); r[2] = f2bf(a.z); r[3] = f2bf(a.w);
    r[4] = f2bf(b.x); r[5] = f2bf(b.y); r[6] = f2bf(b.z); r[7] = f2bf(b.w);
    *(u16x8*)(xbf + i) = r;
  } else {
    // WT[s][e][d] = w[s][d][e], s in 0..2
    const int b2 = bid - 4096;
    const int s = b2 >> 10, r = b2 & 1023;
    const int e0 = (r & 31) * 32, d0 = (r >> 5) * 32;
    const int tx = threadIdx.x & 31, ty = threadIdx.x >> 5;
    const float* in = w + (size_t)s * 1048576;
#pragma unroll
    for (int j = 0; j < 4; ++j)
      tile[ty + j * 8][tx] = in[(size_t)(d0 + ty + j * 8) * 1024 + e0 + tx];
    __syncthreads();
    u16* o = wt + (size_t)s * 1048576;
#pragma unroll
    for (int j = 0; j < 4; ++j)
      o[(size_t)(e0 + ty + j * 8) * 1024 + d0 + tx] = f2bf(tile[tx][ty + j * 8]);
  }
}

// ---------- XCD-aware bijective block swizzle (T1) ----------
// Remaps so each XCD owns a CONTIGUOUS run of logical tiles. WINS when the
// per-XCD working set then fits its 4 MiB L2 (gemm256 grids: r4 FETCH
// 79->59.5 MB). LOSES when contiguity makes each XCD touch the ENTIRE
// B operand (legacy QKV 24x64 grid: all 6 MB of WT per XCD -> L2 thrash;
// measured r0/r12 unswz 64.4us/FETCH 71.9MB vs r9/r11 swz 67.3us/83.8MB).
// Hence the SWZ switch: per-launch choice, evidence-based.

template <int GX, int GY, int GZ, bool EN>
__device__ __forceinline__ void xcd_swz(int& bx, int& by, int& bz) {
  constexpr int NWG = GX * GY * GZ;
  static_assert(NWG % 8 == 0, "grid must be divisible by 8");
  constexpr int Q8 = NWG / 8;
  int flat = blockIdx.x + GX * (blockIdx.y + GY * blockIdx.z);
  if (EN) flat = (flat & 7) * Q8 + (flat >> 3);
  bx = flat % GX;
  by = (flat / GX) % GY;
  bz = flat / (GX * GY);
}

// ================= 256x256 8-phase BT-GEMM =================
// Used ONLY where its grid is exactly tail-free at 1 block/CU (QK: 256
// blocks). For QKV (384 blocks -> 1.5 rounds at 1/CU) the legacy 128^2
// kernel at 2 blocks/CU is measurably faster (r0: 64.3 vs r8: 72.7 us).
// Stage ledger (verified r2/r4): P1 stages (t+1)A1->nxt.A1; P2 none;
// P3 (t+2)B0->cur.B0; P4 (t+2)B1->cur.B1 + (t+2)A0->cur.A0; vmcnt(6) at P4.

__device__ __forceinline__ void stage_half(const u16* __restrict__ g, int ld, int k0,
                                           u16* ldsb, int w, int l) {
  const int srow = l >> 3;                          // row within 8-row chunk
  const int scol = ((l & 7) ^ (srow & 7)) * 8;      // swizzled 16B chunk (u16 units)
#pragma unroll
  for (int q = 0; q < 2; ++q) {
    const int r = w * 16 + q * 8;                   // 8 waves x 2 x 8 rows = 128
    gld_lds16(g + (long)(r + srow) * ld + k0 + scol, (void*)(ldsb + r * 64));
  }
}

template <int EPI, int GX, int GY, int GZ>
__global__ __launch_bounds__(512, 2)
void gemm256_bt(const u16* __restrict__ A, const u16* __restrict__ B,
                void* __restrict__ Cv, int K, int lda, int ldb, int ldc,
                long sA, long sB, long sC,
                u16* __restrict__ auxK, u16* __restrict__ auxV) {
  __shared__ __align__(16) u16 lds[65536];          // 128 KiB

  const int t = threadIdx.x;
  const int w = t >> 6, l = t & 63;
  const int wm = w >> 2, wn = w & 3;
  const int lr = l & 15, lq = l >> 4;
  const int rsw = l & 7;                            // read-side swizzle key
  int bxs, bys, bz;
  xcd_swz<GX, GY, GZ, true>(bxs, bys, bz);
  const int m0 = bys * 256, n0 = bxs * 256;
  const u16* Ar = A + (long)bz * sA + (long)m0 * lda;
  const u16* Br = B + (long)bz * sB + (long)n0 * ldb;

  u16* curA = lds;
  u16* curB = lds + 16384;
  u16* nxtA = lds + 32768;
  u16* nxtB = lds + 49152;

  const int nt = K >> 6;

  f32x4 acc[8][4] = {};

  // ---- prologue: tile0 {A0,B0,B1,A1} -> cur; tile1 {A0,B0,B1} -> nxt ----
  stage_half(Ar,             lda, 0, curA,        w, l);
  stage_half(Br,             ldb, 0, curB,        w, l);
  stage_half(Br + 128 * ldb, ldb, 0, curB + 8192, w, l);
  stage_half(Ar + 128 * lda, lda, 0, curA + 8192, w, l);
  asm volatile("s_waitcnt vmcnt(4)" ::: "memory");
  if (nt > 1) {
    stage_half(Ar,             lda, 64, nxtA,        w, l);
    stage_half(Br,             ldb, 64, nxtB,        w, l);
    stage_half(Br + 128 * ldb, ldb, 64, nxtB + 8192, w, l);
    asm volatile("s_waitcnt vmcnt(6)" ::: "memory");   // tile0 fully landed
  } else {
    asm volatile("s_waitcnt vmcnt(0)" ::: "memory");
  }
  __builtin_amdgcn_s_barrier();

  for (int tt = 0; tt < nt; ++tt) {
    const int kc = tt << 6;
    bf16x8 a0[4][2], a1[4][2], b0[2][2], b1[2][2];

    // -------- phase 1: read A-half-lo(8) + B-quarter-0(4); stage (t+1)A1 ----
#pragma unroll
    for (int mi = 0; mi < 4; ++mi)
#pragma unroll
      for (int j = 0; j < 2; ++j)
        a0[mi][j] = *(const bf16x8*)(curA + (wm * 128 + mi * 16 + lr) * 64 +
                                     (((j * 4 + lq) ^ rsw) * 8));
#pragma unroll
    for (int ni = 0; ni < 2; ++ni)
#pragma unroll
      for (int j = 0; j < 2; ++j)
        b0[ni][j] = *(const bf16x8*)(curB + (wn * 64 + ni * 16 + lr) * 64 +
                                     (((j * 4 + lq) ^ rsw) * 8));
    if (tt + 1 < nt)
      stage_half(Ar + 128 * lda, lda, kc + 64, nxtA + 8192, w, l);
    __builtin_amdgcn_s_barrier();
    asm volatile("s_waitcnt lgkmcnt(0)" ::: "memory");
    __builtin_amdgcn_sched_barrier(0);
    __builtin_amdgcn_s_setprio(1);
#pragma unroll
    for (int mi = 0; mi < 4; ++mi)
#pragma unroll
      for (int ni = 0; ni < 2; ++ni)
#pragma unroll
        for (int j = 0; j < 2; ++j)
          acc[mi][ni] = __builtin_amdgcn_mfma_f32_16x16x32_bf16(a0[mi][j], b0[ni][j], acc[mi][ni], 0, 0, 0);
    __builtin_amdgcn_s_setprio(0);
    __builtin_amdgcn_s_barrier();

    // -------- phase 2: read B-quarter-1(4); no stage (cur.A live till P3) ---
#pragma unroll
    for (int ni = 0; ni < 2; ++ni)
#pragma unroll
      for (int j = 0; j < 2; ++j)
        b1[ni][j] = *(const bf16x8*)(curB + (wn * 64 + (ni + 2) * 16 + lr) * 64 +
                                     (((j * 4 + lq) ^ rsw) * 8));
    __builtin_amdgcn_s_barrier();
    asm volatile("s_waitcnt lgkmcnt(0)" ::: "memory");
    __builtin_amdgcn_sched_barrier(0);
    __builtin_amdgcn_s_setprio(1);
#pragma unroll
    for (int mi = 0; mi < 4; ++mi)
#pragma unroll
      for (int ni = 0; ni < 2; ++ni)
#pragma unroll
        for (int j = 0; j < 2; ++j)
          acc[mi][ni + 2] = __builtin_amdgcn_mfma_f32_16x16x32_bf16(a0[mi][j], b1[ni][j], acc[mi][ni + 2], 0, 0, 0);
    __builtin_amdgcn_s_setprio(0);
    __builtin_amdgcn_s_barrier();

    // -------- phase 3: read A-half-hi(8); stage (t+2)B0 ---------------------
#pragma unroll
    for (int mi = 0; mi < 4; ++mi)
#pragma unroll
      for (int j = 0; j < 2; ++j)
        a1[mi][j] = *(const bf16x8*)(curA + (wm * 128 + (mi + 4) * 16 + lr) * 64 +
                                     (((j * 4 + lq) ^ rsw) * 8));
    if (tt + 2 < nt)
      stage_half(Br, ldb, kc + 128, curB, w, l);
    __builtin_amdgcn_s_barrier();
    asm volatile("s_waitcnt lgkmcnt(0)" ::: "memory");
    __builtin_amdgcn_sched_barrier(0);
    __builtin_amdgcn_s_setprio(1);
#pragma unroll
    for (int mi = 0; mi < 4; ++mi)
#pragma unroll
      for (int ni = 0; ni < 2; ++ni)
#pragma unroll
        for (int j = 0; j < 2; ++j)
          acc[mi + 4][ni + 2] = __builtin_amdgcn_mfma_f32_16x16x32_bf16(a1[mi][j], b1[ni][j], acc[mi + 4][ni + 2], 0, 0, 0);
    __builtin_amdgcn_s_setprio(0);
    __builtin_amdgcn_s_barrier();

    // -------- phase 4: stage (t+2)B1 + (t+2)A0; MFMA hi,lo; tile-end vmcnt --
    if (tt + 2 < nt) {
      stage_half(Br + 128 * ldb, ldb, kc + 128, curB + 8192, w, l);
      stage_half(Ar,             lda, kc + 128, curA,        w, l);
    }
    __builtin_amdgcn_s_barrier();
    __builtin_amdgcn_sched_barrier(0);
    __builtin_amdgcn_s_setprio(1);
#pragma unroll
    for (int mi = 0; mi < 4; ++mi)
#pragma unroll
      for (int ni = 0; ni < 2; ++ni)
#pragma unroll
        for (int j = 0; j < 2; ++j)
          acc[mi + 4][ni] = __builtin_amdgcn_mfma_f32_16x16x32_bf16(a1[mi][j], b0[ni][j], acc[mi + 4][ni], 0, 0, 0);
    __builtin_amdgcn_s_setprio(0);
    if (tt + 2 < nt)      asm volatile("s_waitcnt vmcnt(6)" ::: "memory");
    else if (tt + 1 < nt) asm volatile("s_waitcnt vmcnt(0)" ::: "memory");
    __builtin_amdgcn_s_barrier();

    { u16* x_ = curA; curA = nxtA; nxtA = x_; }
    { u16* y_ = curB; curB = nxtB; nxtB = y_; }
  }

  // ======================= epilogues =======================
  if (EPI == EPI_QK) {
    // Pure exp+store. Rowsum is computed in the PV kernel (it reads the
    // whole P' row anyway) -> no atomics, no cross-block reduction here.
#pragma unroll
    for (int mi = 0; mi < 8; ++mi) {
#pragma unroll
      for (int i = 0; i < 4; ++i) {
        const int row = m0 + wm * 128 + mi * 16 + lq * 4 + i;
#pragma unroll
        for (int ni = 0; ni < 4; ++ni) {
          const int col = n0 + wn * 64 + ni * 16 + lr;
          const u16 h = f2bf(__expf(acc[mi][ni][i] * 0.03125f));  // unnorm prob
          ((u16*)Cv)[(long)bz * sC + (long)row * ldc + col] = h;
        }
      }
    }
    return;
  }

  // EPI_QKV dense (unused in current launch config; kept for completeness)
  u16* qkv_out = (n0 < 1024) ? (u16*)Cv : auxK;
  const int nl0 = n0 & 1023;
#pragma unroll
  for (int mi = 0; mi < 8; ++mi) {
#pragma unroll
    for (int i = 0; i < 4; ++i) {
      const int row = m0 + wm * 128 + mi * 16 + lq * 4 + i;
#pragma unroll
      for (int ni = 0; ni < 4; ++ni)
        qkv_out[(long)row * 1024 + nl0 + wn * 64 + ni * 16 + lr] = f2bf(acc[mi][ni][i]);
    }
  }
  (void)auxV;
}

// ---------- legacy 128x128 BT-GEMM (QKV + PV) ----------
// 4 waves, 34 KiB max LDS -> 2 blocks/CU. QKV grid 24x64 = 1536 = 6/CU,
// tail-free. The 2-blocks/CU inter-block slip (one block computes while the
// other stages) is the throughput mechanism here — r10's fused lockstep
// destroyed it (4x slowdown), so these stay separate kernels.
// SWZ=0 for QKV (r12 confirmed: 64.4us/71.9MB vs swz 67.3us/83.8MB);
// PV keeps SWZ=1 (its measured config, r6: 48.6-50us).
// EPI_QKV: n0<2048 dense Q/K stores; n0>=2048 V-transpose through LDS -> VT.
// EPI_PV rowsum-via-MFMA (this round): rowsum(P') = P' x ones computed on
// the matrix pipe (8 extra MFMA/K-step, B-frag = 1.0) instead of 64 VALU
// adds + shuffles — PV was VALUBusy 35% vs MfmaUtil 26% (r6), so the work
// moves to the idler pipe. Output frag layout (row = lq*4+i, col = any)
// lands each thread's rowsum directly in acc_rs[mi][i]: zero shuffles.
// k-chunk XOR permutation is irrelevant for B=1 (sum is order-invariant);
// each k counted exactly once (chunks {0..7}^rsw bijective).

template <int EPI, int GX, int GY, int GZ, bool SWZ>
__global__ __launch_bounds__(256)
void gemm_bt(const u16* __restrict__ A, const u16* __restrict__ B,
             void* __restrict__ Cv, int K, int lda, int ldb, int ldc,
             long sA, long sB, long sC,
             u16* __restrict__ auxK, u16* __restrict__ auxV) {
  constexpr int LDS_U16 = (EPI == EPI_QKV) ? (128 * 136) : (128 * 128);
  __shared__ __align__(16) u16 lds[LDS_U16];
  u16* As = lds;
  u16* Bs = lds + 128 * 64;

  const int t = threadIdx.x;
  const int w = t >> 6, l = t & 63;
  int bxs, bys, bz;
  xcd_swz<GX, GY, GZ, SWZ>(bxs, bys, bz);
  const u16* Ab = A + (long)bz * sA;
  const u16* Bb = B + (long)bz * sB;
  const int m0 = bys * 128, n0 = bxs * 128;
  const int wm = w & 1, wn = w >> 1;
  const int lr = l & 15, lq = l >> 4;
  const int srow = l >> 3;
  const int scol = ((l & 7) ^ ((l >> 3) & 7)) * 8;
  const int rsw = l & 7;

  f32x4 acc[4][4] = {};
  f32x4 acc_rs[4] = {};                  // EPI_PV: rowsum accumulators
  bf16x8 onesv;
#pragma unroll
  for (int e = 0; e < 8; ++e) onesv[e] = (__bf16)1.0f;

  for (int k0 = 0; k0 < K; k0 += 64) {
    __syncthreads();
#pragma unroll
    for (int c = 0; c < 4; ++c) {
      const int rb = (w * 4 + c) * 8;
      gld_lds16(Ab + (long)(m0 + rb + srow) * lda + k0 + scol, (void*)(As + rb * 64));
      gld_lds16(Bb + (long)(n0 + rb + srow) * ldb + k0 + scol, (void*)(Bs + rb * 64));
    }
    __syncthreads();
#pragma unroll
    for (int j = 0; j < 2; ++j) {
      bf16x8 af[4], bfr[4];
#pragma unroll
      for (int i = 0; i < 4; ++i) {
        const int ch = ((j * 4 + lq) ^ rsw) * 8;
        af[i]  = *(const bf16x8*)(As + (wm * 64 + i * 16 + lr) * 64 + ch);
        bfr[i] = *(const bf16x8*)(Bs + (wn * 64 + i * 16 + lr) * 64 + ch);
      }
      if (EPI == EPI_PV) {
        // rowsum on the MFMA pipe: acc_rs[mi] += af[mi] x ones
#pragma unroll
        for (int mi = 0; mi < 4; ++mi)
          acc_rs[mi] = __builtin_amdgcn_mfma_f32_16x16x32_bf16(af[mi], onesv, acc_rs[mi], 0, 0, 0);
      }
#pragma unroll
      for (int mi = 0; mi < 4; ++mi)
#pragma unroll
        for (int ni = 0; ni < 4; ++ni)
          acc[mi][ni] = __builtin_amdgcn_mfma_f32_16x16x32_bf16(af[mi], bfr[ni], acc[mi][ni], 0, 0, 0);
    }
  }

  if (EPI == EPI_QKV && n0 >= 2048) {
    // ---- V slice: transpose 128x128 tile through LDS, coalesced 16B stores ----
    u16* tp = lds;  // [128 cols][136 rows-padded] u16 = 34816 B
    __syncthreads();  // all frag reads done; safe to overwrite As/Bs
#pragma unroll
    for (int mi = 0; mi < 4; ++mi) {
      const int row0 = wm * 64 + mi * 16 + lq * 4;
#pragma unroll
      for (int ni = 0; ni < 4; ++ni) {
        const int col = wn * 64 + ni * 16 + lr;
        u16x4 v4;
#pragma unroll
        for (int i = 0; i < 4; ++i) v4[i] = f2bf(acc[mi][ni][i]);
        *(u16x4*)(tp + col * 136 + row0) = v4;   // 8B store, 8B-aligned
      }
    }
    __syncthreads();
    const int e0 = n0 - 2048;
    const long bb = m0 >> 11;           // batch
    const int kbase = m0 & 2047;
    u16* vt_base = auxV + bb * 2097152;
#pragma unroll
    for (int q = 0; q < 8; ++q) {
      const int chunk = q * 256 + t;
      const int c = chunk >> 4, r0 = (chunk & 15) * 8;
      u16x8 v = *(const u16x8*)(tp + c * 136 + r0);      // b128, conflict-free
      *(u16x8*)(vt_base + (long)(e0 + c) * 2048 + kbase + r0) = v;  // coalesced
    }
    return;
  }

  u16* qkv_out = nullptr;
  int nl0 = 0;
  if (EPI == EPI_QKV) {
    qkv_out = (n0 < 1024) ? (u16*)Cv : auxK;
    nl0 = n0 & 1023;
  }

#pragma unroll
  for (int mi = 0; mi < 4; ++mi) {
#pragma unroll
    for (int i = 0; i < 4; ++i) {
      const int row = m0 + wm * 64 + mi * 16 + lq * 4 + i;
      float inv;
      if (EPI == EPI_PV) {
        // acc_rs frag layout: row = lq*4 + i in this very lane -> no shuffle
        inv = 1.0f / acc_rs[mi][i];
      }
#pragma unroll
      for (int ni = 0; ni < 4; ++ni) {
        const float val = acc[mi][ni][i];
        const int col = n0 + wn * 64 + ni * 16 + lr;
        if (EPI == EPI_QKV) {
          qkv_out[(long)row * 1024 + nl0 + wn * 64 + ni * 16 + lr] = f2bf(val);
        } else if (EPI == EPI_QK) {
          const u16 h = f2bf(__expf(val * 0.03125f));
          ((u16*)Cv)[(long)bz * sC + (long)row * ldc + col] = h;
        } else {  // EPI_PV
          ((float*)Cv)[(long)bz * sC + (long)row * ldc + col] = val * inv;
        }
      }
    }
  }
}

// ---------- launch ----------

extern "C" void kernel_launch(void* const* d_in, const int* in_sizes, int n_in,
                              void* d_out, int out_size, void* d_ws, size_t ws_size,
                              hipStream_t stream) {
  (void)in_sizes; (void)n_in; (void)out_size;
  const float* x    = (const float*)d_in[0];
  const float* kern = (const float*)d_in[1];
  float* out = (float*)d_out;
  char* ws = (char*)d_ws;
  const size_t MB = 1024 * 1024;
  u16*   xbf  = (u16*)(ws);              // 16 MB: [8192][1024] bf16
  u16*   WT   = (u16*)(ws + 16 * MB);    //  6 MB: [3][1024][1024] bf16
  u16*   Qc   = (u16*)(ws + 22 * MB);    // 16 MB: [8192][1024] bf16
  u16*   Kc   = (u16*)(ws + 38 * MB);    // 16 MB: [8192][1024] bf16
  u16*   VT   = (u16*)(ws + 54 * MB);    // 16 MB: [4][1024e][2048k] bf16
  u16*   SP   = (u16*)(ws + 70 * MB);    // 32 MB: [4][2048][2048] bf16 unnormalized probs
  if (ws_size < 102 * MB)
    fprintf(stderr, "WARNING: ws_size %zu too small\n", ws_size);

  prep_kernel<<<7168, 256, 0, stream>>>(x, xbf, kern, WT);
  // QKV: M=8192, N=3072 (Q|K|V), K=1024; legacy 128^2: 1536 blocks = 6/CU
  // tail-free. SWZ=0: round-robin XCD mapping keeps per-XCD B working set
  // inside L2 (r12 confirmed: 64.4us/71.9MB vs swizzled 67.3us/83.8MB).
  gemm_bt<EPI_QKV, 24, 64, 1, false><<<dim3(24, 64, 1), 256, 0, stream>>>(
      xbf, WT, Qc, 1024, 1024, 1024, 1024, 0, 0, 0, Kc, VT);
  // P'[b][q][k] = exp((Q[b][q,:].K[b][k,:])/32); 256^2: 256 blocks = 1/CU
  gemm256_bt<EPI_QK, 8, 8, 4><<<dim3(8, 8, 4), 512, 0, stream>>>(
      Qc, Kc, SP, 1024, 1024, 1024, 2048,
      2048L * 1024, 2048L * 1024, 2048L * 2048, nullptr, nullptr);
  // out[b][q][e] = (P'[b][q,:] . VT[b][e,:]) / rowsum(P'[b][q,:])
  // rowsum computed in-loop on the MFMA pipe (P' x ones)
  gemm_bt<EPI_PV, 8, 16, 4, true><<<dim3(8, 16, 4), 256, 0, stream>>>(
      SP, VT, out, 2048, 2048, 2048, 1024,
      2048L * 2048, 1024L * 2048, 2048L * 1024, nullptr, nullptr);
}